// Round 1
// baseline (231.414 us; speedup 1.0000x reference)
//
#include <hip/hip_runtime.h>

#define NROWS 131072          // 64*2048
#define D 64
#define K 512
#define TPB 256
#define ROWS_PER_BLOCK (TPB*2)       // 512
#define NBLOCKS (NROWS/ROWS_PER_BLOCK) // 256

#define LOSS_OFF (NROWS*D)           // 8388608
#define PERP_OFF (LOSS_OFF+1)
#define IDX_OFF  (LOSS_OFF+2)

__global__ __launch_bounds__(TPB, 1) void vq_main(
    const float* __restrict__ x, const float* __restrict__ emb,
    float* __restrict__ out, float* __restrict__ wsum, int* __restrict__ whist)
{
    __shared__ float sE[K*D];     // 128 KiB codebook
    __shared__ float sE2[K];      // ||e||^2

    // stage codebook (coalesced float4)
    for (int i = threadIdx.x; i < (K*D)/4; i += TPB)
        reinterpret_cast<float4*>(sE)[i] = reinterpret_cast<const float4*>(emb)[i];
    __syncthreads();

    // code norms
    for (int k = threadIdx.x; k < K; k += TPB) {
        const float* e = &sE[k*D];
        float s0=0.f,s1=0.f,s2=0.f,s3=0.f;
        #pragma unroll
        for (int d=0; d<D; d+=4) {
            s0 = fmaf(e[d+0], e[d+0], s0);
            s1 = fmaf(e[d+1], e[d+1], s1);
            s2 = fmaf(e[d+2], e[d+2], s2);
            s3 = fmaf(e[d+3], e[d+3], s3);
        }
        sE2[k] = (s0+s1)+(s2+s3);
    }
    __syncthreads();

    const int r0 = blockIdx.x * ROWS_PER_BLOCK + threadIdx.x;
    const int r1 = r0 + TPB;

    // rows into registers
    float xa[D], xb[D];
    {
        const float4* pa = reinterpret_cast<const float4*>(x + (size_t)r0 * D);
        const float4* pb = reinterpret_cast<const float4*>(x + (size_t)r1 * D);
        #pragma unroll
        for (int i = 0; i < D/4; ++i) {
            float4 va = pa[i], vb = pb[i];
            xa[4*i+0]=va.x; xa[4*i+1]=va.y; xa[4*i+2]=va.z; xa[4*i+3]=va.w;
            xb[4*i+0]=vb.x; xb[4*i+1]=vb.y; xb[4*i+2]=vb.z; xb[4*i+3]=vb.w;
        }
    }

    float bestA = 3.4e38f, bestB = 3.4e38f;
    int   ia = 0, ib = 0;

    #pragma unroll 2
    for (int k = 0; k < K; ++k) {
        const float* e = &sE[k*D];
        float a0=0.f,a1=0.f,a2=0.f,a3=0.f;
        float b0=0.f,b1=0.f,b2=0.f,b3=0.f;
        #pragma unroll
        for (int d = 0; d < D; d += 4) {
            float e0=e[d+0], e1=e[d+1], e2=e[d+2], e3=e[d+3];
            a0 = fmaf(xa[d+0], e0, a0);
            a1 = fmaf(xa[d+1], e1, a1);
            a2 = fmaf(xa[d+2], e2, a2);
            a3 = fmaf(xa[d+3], e3, a3);
            b0 = fmaf(xb[d+0], e0, b0);
            b1 = fmaf(xb[d+1], e1, b1);
            b2 = fmaf(xb[d+2], e2, b2);
            b3 = fmaf(xb[d+3], e3, b3);
        }
        float da = fmaf(-2.f, (a0+a1)+(a2+a3), sE2[k]);
        float db = fmaf(-2.f, (b0+b1)+(b2+b3), sE2[k]);
        if (da < bestA) { bestA = da; ia = k; }   // strict < : first-min like argmin
        if (db < bestB) { bestB = db; ib = k; }
    }

    // epilogue: gather, straight-through output (x + (q - x) to match ref rounding),
    // squared-diff accumulation, index write, histogram
    float dsum = 0.f;
    {
        const float4* ea = reinterpret_cast<const float4*>(&sE[ia*D]);
        const float4* eb = reinterpret_cast<const float4*>(&sE[ib*D]);
        float4* oa = reinterpret_cast<float4*>(out + (size_t)r0 * D);
        float4* ob = reinterpret_cast<float4*>(out + (size_t)r1 * D);
        #pragma unroll
        for (int i = 0; i < D/4; ++i) {
            float4 qa = ea[i], qb = eb[i];
            float d0,d1,d2,d3;
            float4 va, vb;
            d0 = qa.x - xa[4*i+0]; va.x = xa[4*i+0] + d0; dsum = fmaf(d0,d0,dsum);
            d1 = qa.y - xa[4*i+1]; va.y = xa[4*i+1] + d1; dsum = fmaf(d1,d1,dsum);
            d2 = qa.z - xa[4*i+2]; va.z = xa[4*i+2] + d2; dsum = fmaf(d2,d2,dsum);
            d3 = qa.w - xa[4*i+3]; va.w = xa[4*i+3] + d3; dsum = fmaf(d3,d3,dsum);
            oa[i] = va;
            d0 = qb.x - xb[4*i+0]; vb.x = xb[4*i+0] + d0; dsum = fmaf(d0,d0,dsum);
            d1 = qb.y - xb[4*i+1]; vb.y = xb[4*i+1] + d1; dsum = fmaf(d1,d1,dsum);
            d2 = qb.z - xb[4*i+2]; vb.z = xb[4*i+2] + d2; dsum = fmaf(d2,d2,dsum);
            d3 = qb.w - xb[4*i+3]; vb.w = xb[4*i+3] + d3; dsum = fmaf(d3,d3,dsum);
            ob[i] = vb;
        }
    }

    out[IDX_OFF + r0] = (float)ia;
    out[IDX_OFF + r1] = (float)ib;

    atomicAdd(&whist[ia], 1);
    atomicAdd(&whist[ib], 1);

    // wave reduction of squared-diff sum, one atomic per wave
    #pragma unroll
    for (int off = 32; off > 0; off >>= 1)
        dsum += __shfl_xor(dsum, off, 64);
    if ((threadIdx.x & 63) == 0)
        atomicAdd(wsum, dsum);
}

__global__ __launch_bounds__(K) void vq_finalize(
    const float* __restrict__ wsum, const int* __restrict__ whist,
    float* __restrict__ out)
{
    __shared__ float red[K];
    int t = threadIdx.x;
    float c = (float)whist[t];
    float p = c / (float)NROWS;
    red[t] = p * logf(p + 1e-10f);
    __syncthreads();
    for (int s = K/2; s > 0; s >>= 1) {
        if (t < s) red[t] += red[t+s];
        __syncthreads();
    }
    if (t == 0) {
        out[PERP_OFF] = expf(-red[0]);
        out[LOSS_OFF] = 0.25f * (wsum[0] / (float)(NROWS*D));
    }
}

extern "C" void kernel_launch(void* const* d_in, const int* in_sizes, int n_in,
                              void* d_out, int out_size, void* d_ws, size_t ws_size,
                              hipStream_t stream)
{
    const float* x   = (const float*)d_in[0];
    const float* emb = (const float*)d_in[1];
    float* out   = (float*)d_out;
    float* wsum  = (float*)d_ws;                       // 1 float at offset 0
    int*   whist = (int*)((char*)d_ws + 64);           // 512 ints at offset 64

    hipMemsetAsync(d_ws, 0, 64 + K * sizeof(int), stream);
    vq_main<<<NBLOCKS, TPB, 0, stream>>>(x, emb, out, wsum, whist);
    vq_finalize<<<1, K, 0, stream>>>(wsum, whist, out);
}